// Round 2
// baseline (173.330 us; speedup 1.0000x reference)
//
#include <hip/hip_runtime.h>
#include <math.h>

#define NQ      12
#define DIM     4096
#define LAYERS  8
#define FEAT    3072
#define NCLASS  10
#define STRIDE  66   // padded LDS row stride (floats)

typedef float v2f __attribute__((ext_vector_type(2)));
typedef float v4f __attribute__((ext_vector_type(4)));

// prefix-xor (inverse Gray) of a 6-bit value; folds to a constant for unrolled r
__device__ __forceinline__ int px6c(int r) {
    int u = r ^ (r >> 1); u ^= u >> 2; u ^= u >> 4; return u;
}
__device__ __forceinline__ int gray6(int r) { return r ^ (r >> 1); }

// 6 in-register qubit butterflies over v2[32] (covers reg bits 0..5 of r = 2i+comp).
// Reg bit p uses c = cl[off-p], s = sl[off-p].
__device__ __forceinline__ void butterflies6(v2f v2[32],
                                             const float* __restrict__ cl,
                                             const float* __restrict__ sl,
                                             int off) {
    // p = 0: butterfly within the float2 pair -> packed with swapped operand
    {
        const float c = cl[off], s = sl[off];
        const v2f c2 = {c, c};
        const v2f ms = {-s, s};
#pragma unroll
        for (int i = 0; i < 32; ++i) {
            v2f a = v2[i];
            v2f sw = {a.y, a.x};
            v2[i] = a * c2 + sw * ms;   // (c*x - s*y, s*x + c*y)
        }
    }
    // p = 1..5: butterfly across v2 elements, both components identical -> v_pk_*
#pragma unroll
    for (int p = 1; p < 6; ++p) {
        const float c = cl[off - p], s = sl[off - p];
        const v2f c2 = {c, c};
        const v2f s2 = {s, s};
#pragma unroll
        for (int i0 = 0; i0 < 32; ++i0) {
            if (i0 & (1 << (p - 1))) continue;
            const int i1 = i0 | (1 << (p - 1));
            v2f a = v2[i0], e = v2[i1];
            v2[i0] = a * c2 - e * s2;
            v2[i1] = a * s2 + e * c2;
        }
    }
}

__global__ __launch_bounds__(64)
void qnn_kernel(const float* __restrict__ x,
                const float* __restrict__ ang,
                const float* __restrict__ W,
                const float* __restrict__ bias,
                float* __restrict__ out)
{
    __shared__ float lds[STRIDE * 64];      // 16896 B; also reused for q[] in epilogue
    __shared__ float cst[LAYERS * NQ];
    __shared__ float snt[LAYERS * NQ];

    const int t = threadIdx.x;              // 0..63, one wave per block/state
    const int b = blockIdx.x;

    // ---- trig tables (96 angles) ----
    {
        float a0 = ang[t];
        cst[t] = cosf(a0);
        snt[t] = sinf(a0);
        if (t < LAYERS * NQ - 64) {
            float a1 = ang[64 + t];
            cst[64 + t] = cosf(a1);
            snt[64 + t] = sinf(a1);
        }
    }

    // ---- load psi0 (unnormalized), A layout: v2[i] = (psi[64t+2i], psi[64t+2i+1]) ----
    v2f v2[32];
    {
        const float* xr = x + (size_t)b * FEAT + 64 * t;
        if (t < FEAT / 64) {                // t < 48: real features
#pragma unroll
            for (int j = 0; j < 16; ++j) {
                float4 f4 = *(const float4*)(xr + 4 * j);
                v2f lo = {f4.x, f4.y};
                v2f hi = {f4.z, f4.w};
                v2[2 * j] = lo;
                v2[2 * j + 1] = hi;
            }
        } else {
            const v2f z = {0.f, 0.f};
#pragma unroll
            for (int i = 0; i < 32; ++i) v2[i] = z;
        }
    }

    // ---- ||x||^2 (normalization deferred: circuit is linear) ----
    v2f ss2 = {0.f, 0.f};
#pragma unroll
    for (int i = 0; i < 32; ++i) ss2 = v2[i] * v2[i] + ss2;
    float ss = ss2.x + ss2.y;
#pragma unroll
    for (int o = 1; o < 64; o <<= 1) ss += __shfl_xor(ss, o, 64);
    const float invn2 = 1.0f / ss;

    // per-lane helpers for the Gray-permutation-folded reads
    int px = t ^ (t >> 1); px ^= px >> 2; px ^= px >> 4;   // px6(t)
    const int flip = px & 1;                                // parity(t)
    const int base = px + (flip ? STRIDE * 63 : 0);         // K^63 = 63-K trick
    const int dsg  = flip ? -1 : 1;

    __syncthreads();   // tables ready

#pragma unroll 1
    for (int l = 0; l < LAYERS; ++l) {
        const float* cl = cst + l * NQ;
        const float* sl = snt + l * NQ;

        // ---- phase A: reg bit p == index bit p -> qubit (11-p) ----
        butterflies6(v2, cl, sl, 11);

        // ---- A -> LDS: psi[64t+r] at f = t + STRIDE*r (conflict-free) ----
#pragma unroll
        for (int i = 0; i < 32; ++i) {
            lds[t + STRIDE * (2 * i)]     = v2[i].x;
            lds[t + STRIDE * (2 * i + 1)] = v2[i].y;
        }
        __syncthreads();

        // ---- LDS -> B: v2[i] = (psi[64(2i)+t], psi[64(2i+1)+t]), b64, 2-way max ----
#pragma unroll
        for (int i = 0; i < 32; ++i) {
            v2[i] = *(const v2f*)(lds + STRIDE * t + 2 * i);
        }

        // ---- phase B: reg bit p == index bit (6+p) -> qubit (5-p) ----
        butterflies6(v2, cl, sl, 5);

        if (l == LAYERS - 1) break;  // last layer: Gray perm folds into epilogue

        // ---- B -> LDS (own-lane addresses) ----
#pragma unroll
        for (int i = 0; i < 32; ++i) {
            *(v2f*)(lds + STRIDE * t + 2 * i) = v2[i];
        }
        __syncthreads();

        // ---- LDS -> A with CNOT-cascade (Gray) perm folded:
        //      v[r] = psi[ginv(64t + r)]; addr = base + dsg*(STRIDE*px6c(r)) ----
#pragma unroll
        for (int i = 0; i < 32; ++i) {
            const int k0 = STRIDE * px6c(2 * i);        // compile-time constants
            const int k1 = STRIDE * (px6c(2 * i) ^ 1);
            v2f nv;
            nv.x = lds[base + dsg * k0];
            nv.y = lds[base + dsg * k1];
            v2[i] = nv;
        }
        __syncthreads();  // fence before next layer's A->LDS overwrite
    }

    // ---- epilogue: q[g(j)] = psi[j]^2 scattered to LDS, then coalesced q.W ----
    // B layout: j = 64r + t; g(j) = 64*gray6(r) + (gray6(t) ^ ((r&1)<<5))
    const int gt = gray6(t);
#pragma unroll
    for (int i = 0; i < 32; ++i) {
        const int g0 = 64 * gray6(2 * i);               // compile-time constants
        const int g1 = 64 * (gray6(2 * i) ^ 1);
        lds[g0 + gt]        = v2[i].x * v2[i].x;        // bank = gt&31: 2-way, free
        lds[g1 + (gt ^ 32)] = v2[i].y * v2[i].y;
    }
    __syncthreads();

    v4f acc[NCLASS];
#pragma unroll
    for (int c = 0; c < NCLASS; ++c) acc[c] = (v4f){0.f, 0.f, 0.f, 0.f};

#pragma unroll
    for (int k = 0; k < 16; ++k) {
        const v4f q4 = *(const v4f*)(lds + 4 * t + 256 * k);   // coalesced b128
#pragma unroll
        for (int c = 0; c < NCLASS; ++c) {
            const v4f w4 = *(const v4f*)(W + c * DIM + 4 * t + 256 * k); // dwordx4
            acc[c] = q4 * w4 + acc[c];
        }
    }

#pragma unroll
    for (int c = 0; c < NCLASS; ++c) {
        float a = (acc[c].x + acc[c].y) + (acc[c].z + acc[c].w);
#pragma unroll
        for (int o = 1; o < 64; o <<= 1) a += __shfl_xor(a, o, 64);
        if (t == 0) out[b * NCLASS + c] = fmaf(a, invn2, bias[c]);
    }
}

extern "C" void kernel_launch(void* const* d_in, const int* in_sizes, int n_in,
                              void* d_out, int out_size, void* d_ws, size_t ws_size,
                              hipStream_t stream) {
    const float* x    = (const float*)d_in[0];
    const float* ang  = (const float*)d_in[1];
    const float* W    = (const float*)d_in[2];
    const float* bias = (const float*)d_in[3];
    float* out = (float*)d_out;
    const int batch = in_sizes[0] / FEAT;   // 2048
    qnn_kernel<<<batch, 64, 0, stream>>>(x, ang, W, bias, out);
}

// Round 3
// 123.743 us; speedup vs baseline: 1.4007x; 1.4007x over previous
//
#include <hip/hip_runtime.h>
#include <math.h>

#define NQ      12
#define DIM     4096
#define LAYERS  8
#define FEAT    3072
#define NCLASS  10
#define STRIDE  66   // padded LDS row stride (floats)

typedef float v2f __attribute__((ext_vector_type(2)));
typedef float v4f __attribute__((ext_vector_type(4)));

// prefix-xor (inverse Gray) of a 6-bit value; folds to a constant for unrolled r
__device__ __forceinline__ int px6c(int r) {
    int u = r ^ (r >> 1); u ^= u >> 2; u ^= u >> 4; return u;
}
__device__ __forceinline__ int gray6(int r) { return r ^ (r >> 1); }

// 6 in-register qubit butterflies over v2[32] (reg bits 0..5 of r = 2i+comp).
// Reg bit p uses c = cl[off-p], s = sl[off-p]. Emits v_pk_* packed fp32.
__device__ __forceinline__ void butterflies6(v2f v2[32],
                                             const float* __restrict__ cl,
                                             const float* __restrict__ sl,
                                             int off) {
    // p = 0: butterfly within the float2 pair (swapped operand -> op_sel packing)
    {
        const float c = cl[off], s = sl[off];
        const v2f c2 = {c, c};
        const v2f ms = {-s, s};
#pragma unroll
        for (int i = 0; i < 32; ++i) {
            v2f a = v2[i];
            v2f sw = {a.y, a.x};
            v2[i] = a * c2 + sw * ms;   // (c*x - s*y, s*x + c*y)
        }
    }
    // p = 1..5: butterfly across v2 elements, both components identical -> v_pk_*
#pragma unroll
    for (int p = 1; p < 6; ++p) {
        const float c = cl[off - p], s = sl[off - p];
        const v2f c2 = {c, c};
        const v2f s2 = {s, s};
#pragma unroll
        for (int i0 = 0; i0 < 32; ++i0) {
            if (i0 & (1 << (p - 1))) continue;
            const int i1 = i0 | (1 << (p - 1));
            v2f a = v2[i0], e = v2[i1];
            v2[i0] = a * c2 - e * s2;
            v2[i1] = a * s2 + e * c2;
        }
    }
}

__global__ __launch_bounds__(64)
void qnn_kernel(const float* __restrict__ x,
                const float* __restrict__ ang,
                const float* __restrict__ W,
                const float* __restrict__ bias,
                float* __restrict__ out)
{
    __shared__ float lds[STRIDE * 64];      // 16896 B; reused for q[] in epilogue
    __shared__ float cst[LAYERS * NQ];
    __shared__ float snt[LAYERS * NQ];

    const int t = threadIdx.x;              // 0..63, one wave per block/state
    const int b = blockIdx.x;

    // ---- trig tables (96 angles) ----
    {
        float a0 = ang[t];
        cst[t] = cosf(a0);
        snt[t] = sinf(a0);
        if (t < LAYERS * NQ - 64) {
            float a1 = ang[64 + t];
            cst[64 + t] = cosf(a1);
            snt[64 + t] = sinf(a1);
        }
    }

    // ---- load psi0 (unnormalized), A layout: v2[i] = (psi[64t+2i], psi[64t+2i+1]) ----
    v2f v2[32];
    {
        const float* xr = x + (size_t)b * FEAT + 64 * t;
        if (t < FEAT / 64) {                // t < 48: real features
#pragma unroll
            for (int j = 0; j < 16; ++j) {
                float4 f4 = *(const float4*)(xr + 4 * j);
                v2f lo = {f4.x, f4.y};
                v2f hi = {f4.z, f4.w};
                v2[2 * j] = lo;
                v2[2 * j + 1] = hi;
            }
        } else {
            const v2f z = {0.f, 0.f};
#pragma unroll
            for (int i = 0; i < 32; ++i) v2[i] = z;
        }
    }

    // ---- ||x||^2 (normalization deferred: circuit is linear) ----
    v2f ss2 = {0.f, 0.f};
#pragma unroll
    for (int i = 0; i < 32; ++i) ss2 = v2[i] * v2[i] + ss2;
    float ss = ss2.x + ss2.y;
#pragma unroll
    for (int o = 1; o < 64; o <<= 1) ss += __shfl_xor(ss, o, 64);
    const float invn2 = 1.0f / ss;

    // per-lane helpers for the Gray-permutation-folded reads
    int px = t ^ (t >> 1); px ^= px >> 2; px ^= px >> 4;   // px6(t)
    const int flip = px & 1;                                // parity(t)
    const int base = px + (flip ? STRIDE * 63 : 0);         // K^63 = 63-K trick
    const int dsg  = flip ? -1 : 1;

    __syncthreads();   // tables ready

#pragma unroll 1
    for (int l = 0; l < LAYERS; ++l) {
        const float* cl = cst + l * NQ;
        const float* sl = snt + l * NQ;

        // ---- phase A: reg bit p == index bit p -> qubit (11-p) ----
        butterflies6(v2, cl, sl, 11);

        // ---- A -> LDS: psi[64t+r] at f = t + STRIDE*r (conflict-free) ----
#pragma unroll
        for (int i = 0; i < 32; ++i) {
            lds[t + STRIDE * (2 * i)]     = v2[i].x;
            lds[t + STRIDE * (2 * i + 1)] = v2[i].y;
        }
        __syncthreads();

        // ---- LDS -> B: v2[i] = (psi[64(2i)+t], psi[64(2i+1)+t]), b64, 2-way max ----
#pragma unroll
        for (int i = 0; i < 32; ++i) {
            v2[i] = *(const v2f*)(lds + STRIDE * t + 2 * i);
        }

        // ---- phase B: reg bit p == index bit (6+p) -> qubit (5-p) ----
        butterflies6(v2, cl, sl, 5);

        if (l == LAYERS - 1) break;  // last layer: Gray perm folds into epilogue

        // ---- B -> LDS (own-lane addresses) ----
#pragma unroll
        for (int i = 0; i < 32; ++i) {
            *(v2f*)(lds + STRIDE * t + 2 * i) = v2[i];
        }
        __syncthreads();

        // ---- LDS -> A with CNOT-cascade (Gray) perm folded:
        //      v[r] = psi[ginv(64t + r)]; addr = base + dsg*(STRIDE*px6c(r)) ----
#pragma unroll
        for (int i = 0; i < 32; ++i) {
            const int k0 = STRIDE * px6c(2 * i);        // compile-time constants
            const int k1 = STRIDE * (px6c(2 * i) ^ 1);
            v2f nv;
            nv.x = lds[base + dsg * k0];
            nv.y = lds[base + dsg * k1];
            v2[i] = nv;
        }
        __syncthreads();  // fence before next layer's A->LDS overwrite
    }

    // ---- epilogue: q[g(j)] = psi[j]^2 scattered to LDS (B layout j = 64r + t;
    //      g(j) = 64*gray6(r) + (gray6(t) ^ ((r&1)<<5))), then coalesced q.W ----
    const int gt = gray6(t);
    __syncthreads();   // lds still holds last B->LDS? no — last layer skipped it; fence Gray reads of layer 6 done
#pragma unroll
    for (int i = 0; i < 32; ++i) {
        const int g0 = 64 * gray6(2 * i);               // compile-time constants
        const int g1 = 64 * (gray6(2 * i) ^ 1);
        lds[g0 + gt]        = v2[i].x * v2[i].x;        // bank = gt&31: 2-way, free
        lds[g1 + (gt ^ 32)] = v2[i].y * v2[i].y;
    }
    __syncthreads();

    // low-pressure dot products: loads consumed immediately, scalar accumulators
    float acc[NCLASS];
#pragma unroll
    for (int c = 0; c < NCLASS; ++c) acc[c] = 0.f;

#pragma unroll 1
    for (int k = 0; k < 16; ++k) {
        const v4f q4 = *(const v4f*)(lds + 4 * t + 256 * k);   // b128, conflict-free
#pragma unroll
        for (int c = 0; c < NCLASS; ++c) {
            const v4f w4 = *(const v4f*)(W + c * DIM + 4 * t + 256 * k); // dwordx4
            acc[c] += q4.x * w4.x + q4.y * w4.y + q4.z * w4.z + q4.w * w4.w;
        }
    }

#pragma unroll
    for (int c = 0; c < NCLASS; ++c) {
        float a = acc[c];
#pragma unroll
        for (int o = 1; o < 64; o <<= 1) a += __shfl_xor(a, o, 64);
        if (t == 0) out[b * NCLASS + c] = fmaf(a, invn2, bias[c]);
    }
}

extern "C" void kernel_launch(void* const* d_in, const int* in_sizes, int n_in,
                              void* d_out, int out_size, void* d_ws, size_t ws_size,
                              hipStream_t stream) {
    const float* x    = (const float*)d_in[0];
    const float* ang  = (const float*)d_in[1];
    const float* W    = (const float*)d_in[2];
    const float* bias = (const float*)d_in[3];
    float* out = (float*)d_out;
    const int batch = in_sizes[0] / FEAT;   // 2048
    qnn_kernel<<<batch, 64, 0, stream>>>(x, ang, W, bias, out);
}